// Round 3
// baseline (4325.559 us; speedup 1.0000x reference)
//
#include <hip/hip_runtime.h>
#include <cstddef>
#include <cstdint>

#define PI_F 3.14159265358979323846f

typedef __attribute__((ext_vector_type(8))) short short8;   // 8 bf16 = 4 VGPRs
typedef __attribute__((ext_vector_type(4))) float floatx4;  // MFMA acc

__device__ __forceinline__ short f2bf(float f) {
    union { float f; unsigned u; } v; v.f = f;
    unsigned r = v.u + 0x7FFFu + ((v.u >> 16) & 1u);   // RNE
    return (short)(r >> 16);
}

// ---------------------------------------------------------------------------
// Grid: per (ho, tap) fractional row and longitude-offset (px). Exact port of
// _make_grid. rows_g/dcol_g are (Ho * K2).
// ---------------------------------------------------------------------------
__global__ __launch_bounds__(256) void make_grid_kernel(
    float* __restrict__ rows_g, float* __restrict__ dcol_g,
    int Ho, int K2, int k, int H, int W, int stride, float delta)
{
    int tid = blockIdx.x * 256 + threadIdx.x;
    if (tid >= Ho * K2) return;
    int ho = tid / K2;
    int i  = tid - ho * K2;
    int jy = i / k, jx = i - jy * k;
    float half = (k - 1) * 0.5f;
    float yy = tanf(delta / (float)k * ((float)jy - half));
    float xx = tanf(delta / (float)k * ((float)jx - half));
    float rho = sqrtf(xx * xx + yy * yy);
    float rho_s = (rho == 0.f) ? 1.f : rho;
    float nu = atanf(rho);
    float lat0 = PI_F * 0.5f - ((float)(ho * stride) + 0.5f) * (PI_F / (float)H);
    float sl = sinf(lat0), cl = cosf(lat0);
    float sn = sinf(nu),  cn = cosf(nu);
    float arg = cn * sl + (yy / rho_s) * sn * cl;
    arg = fminf(1.f, fmaxf(-1.f, arg));
    float lat = asinf(arg);
    float dlon = atan2f(xx * sn, rho * cl * cn - yy * sl * sn);
    rows_g[tid] = (PI_F * 0.5f - lat) / PI_F * (float)H - 0.5f;
    dcol_g[tid] = dlon / (2.f * PI_F) * (float)W;
}

// ---------------------------------------------------------------------------
// Fused spherical-conv GEMM, bf16 MFMA.
//   Y[b][m][ho][wo] = sum_k A[m][k] * patch(n,k) + bias[m]
// Block tile 128x128, BK=32, 256 threads = 4 waves; each wave computes a
// 64x64 quadrant as 4x4 tiles of v_mfma_f32_16x16x32_bf16.
// B tile built by on-the-fly bilinear gather (lat clamp, lon wrap, optional
// nearest-2x upsample for src1 channels -> fuses up2+concat).
// LDS layout: K-contiguous rows, stride 40 shorts (80B) -> 2-way bank
// aliasing only (free), 16B-aligned for ds_read_b128 fragments.
// ---------------------------------------------------------------------------
#define BMT 128
#define BNT 128
#define BKT 32
#define LDK 40

__global__ __launch_bounds__(256) void sconv_mfma_kernel(
    const float* __restrict__ A, const float* __restrict__ bias,
    const float* __restrict__ src1, const float* __restrict__ src2,
    int C1, int C2, int H, int W, int up1,
    const float* __restrict__ rows_g, const float* __restrict__ dcol_g,
    int K2, int stride, int lWo, int lHo,
    float* __restrict__ Y, int M, int K, int N)
{
    __shared__ short As[BMT][LDK];
    __shared__ short Bs[BNT][LDK];
    const int tid = threadIdx.x;
    const int n0  = blockIdx.x * BNT;
    const int m0  = blockIdx.y * BMT;
    const int Wo  = 1 << lWo;
    const int Ho  = 1 << lHo;
    const int HW  = 1 << (lWo + lHo);
    const int lW  = 31 - __clz(W);   // W is a power of two

    // ---- A staging mapping: thread -> (row m, half of K-tile) ----
    const int am   = tid >> 1;        // 0..127
    const int ah   = tid & 1;         // 0/1 -> k offset 0/16
    const int amg  = m0 + am;
    const bool amv = (amg < M);

    // ---- B staging mapping: thread -> (col n, half of K-tile) ----
    const int bn  = tid & 127;        // 0..127
    const int bh  = tid >> 7;         // 0/1
    const int n_s = n0 + bn;          // N is a multiple of 128
    const int wo_s = n_s & (Wo - 1);
    const int r_s  = n_s >> lWo;
    const int ho_s = r_s & (Ho - 1);
    const int b_s  = r_s >> lHo;
    const float* rg = rows_g + ho_s * K2;
    const float* dg = dcol_g + ho_s * K2;
    const float wo_px = (float)(wo_s * stride);
    const int Hs = H >> up1, Ws = W >> up1;
    const size_t plane1 = (size_t)(Hs * Ws);
    const size_t plane2 = (size_t)(H * W);
    const float* base1 = src1 + (size_t)b_s * C1 * plane1;
    const float* base2 = src2 ? (src2 + (size_t)b_s * C2 * plane2) : (const float*)0;

    // ---- wave/lane decomposition for MFMA ----
    const int wave = tid >> 6;
    const int wm   = (wave & 1) * 64;
    const int wn   = (wave >> 1) * 64;
    const int lane = tid & 63;
    const int l16  = lane & 15;
    const int quad = lane >> 4;

    floatx4 acc[4][4];
#pragma unroll
    for (int i = 0; i < 4; i++)
#pragma unroll
        for (int j = 0; j < 4; j++)
            acc[i][j] = (floatx4){0.f, 0.f, 0.f, 0.f};

    for (int k0 = 0; k0 < K; k0 += BKT) {
        // ---- A tile: fp32 -> bf16, rows of 16 consecutive k ----
        {
            const int kb = k0 + ah * 16;
            short t[16];
            const float* ap = A + (size_t)amg * K + kb;
#pragma unroll
            for (int j = 0; j < 16; j++)
                t[j] = (amv && kb + j < K) ? f2bf(ap[j]) : (short)0;
            *(short8*)&As[am][ah * 16]     = *(short8*)&t[0];
            *(short8*)&As[am][ah * 16 + 8] = *(short8*)&t[8];
        }
        // ---- B tile: bilinear gather -> bf16 ----
        {
            const int kb = k0 + bh * 16;
            int c   = (unsigned)kb / (unsigned)K2;
            int tap = kb - c * K2;
            short t[16];
#pragma unroll
            for (int j = 0; j < 16; j++) {
                float v = 0.f;
                if (kb + j < K) {
                    float row = rg[tap];
                    float col = wo_px + dg[tap];
                    float r0f = floorf(row); float fr = row - r0f;
                    float c0f = floorf(col); float fc = col - c0f;
                    int r0  = (int)r0f;
                    int r0i = min(max(r0, 0), H - 1);
                    int r1i = min(max(r0 + 1, 0), H - 1);
                    int c0  = ((int)c0f) & (W - 1);
                    int c1  = (c0 + 1) & (W - 1);
                    float v00, v01, v10, v11;
                    if (c < C1) {
                        const float* p = base1 + (size_t)c * plane1;
                        int ra = r0i >> up1, rb = r1i >> up1;
                        int ca = c0 >> up1,  cb = c1 >> up1;
                        v00 = p[ra * Ws + ca]; v01 = p[ra * Ws + cb];
                        v10 = p[rb * Ws + ca]; v11 = p[rb * Ws + cb];
                    } else {
                        const float* p = base2 + (size_t)(c - C1) * plane2;
                        v00 = p[r0i * W + c0]; v01 = p[r0i * W + c1];
                        v10 = p[r1i * W + c0]; v11 = p[r1i * W + c1];
                    }
                    v = (1.f - fr) * ((1.f - fc) * v00 + fc * v01)
                      +        fr  * ((1.f - fc) * v10 + fc * v11);
                }
                t[j] = f2bf(v);
                if (++tap == K2) { tap = 0; ++c; }
            }
            *(short8*)&Bs[bn][bh * 16]     = *(short8*)&t[0];
            *(short8*)&Bs[bn][bh * 16 + 8] = *(short8*)&t[8];
        }
        __syncthreads();

        short8 af[4], bf[4];
#pragma unroll
        for (int i = 0; i < 4; i++)
            af[i] = *(const short8*)&As[wm + i * 16 + l16][quad * 8];
#pragma unroll
        for (int j = 0; j < 4; j++)
            bf[j] = *(const short8*)&Bs[wn + j * 16 + l16][quad * 8];
#pragma unroll
        for (int i = 0; i < 4; i++)
#pragma unroll
            for (int j = 0; j < 4; j++)
                acc[i][j] = __builtin_amdgcn_mfma_f32_16x16x32_bf16(
                    af[i], bf[j], acc[i][j], 0, 0, 0);
        __syncthreads();
    }

    // ---- epilogue: C/D layout col=lane&15, row=quad*4+reg ----
#pragma unroll
    for (int i = 0; i < 4; i++) {
#pragma unroll
        for (int j = 0; j < 4; j++) {
            const int n = n0 + wn + j * 16 + l16;
            const int wo = n & (Wo - 1);
            const int r  = n >> lWo;
            const int ho = r & (Ho - 1);
            const int b_ = r >> lHo;
#pragma unroll
            for (int rr = 0; rr < 4; rr++) {
                const int m = m0 + wm + i * 16 + quad * 4 + rr;
                if (m < M)
                    Y[((size_t)b_ * M + m) * HW + (ho << lWo) + wo] =
                        acc[i][j][rr] + bias[m];
            }
        }
    }
}

// ---------------------------------------------------------------------------
// BN stats: one block per channel; mean + biased var over (B, Ho, Wo).
// ---------------------------------------------------------------------------
__global__ __launch_bounds__(256) void bn_stats_kernel(
    const float* __restrict__ Y, float* __restrict__ stats,
    int Co, int HW, int B)
{
    int co = blockIdx.x;
    int tid = threadIdx.x;
    int Nt = B * HW;
    double s = 0.0, s2 = 0.0;
    for (int idx = tid; idx < Nt; idx += 256) {
        int b = idx / HW; int sp = idx - b * HW;
        float v = Y[((size_t)b * Co + co) * HW + sp];
        s += v; s2 += (double)v * v;
    }
    __shared__ double sh_s[256], sh_s2[256];
    sh_s[tid] = s; sh_s2[tid] = s2;
    __syncthreads();
    for (int off = 128; off > 0; off >>= 1) {
        if (tid < off) { sh_s[tid] += sh_s[tid + off]; sh_s2[tid] += sh_s2[tid + off]; }
        __syncthreads();
    }
    if (tid == 0) {
        double mean = sh_s[0] / Nt;
        double var = sh_s2[0] / Nt - mean * mean;
        if (var < 0.0) var = 0.0;
        stats[co * 2]     = (float)mean;
        stats[co * 2 + 1] = (float)var;
    }
}

__global__ __launch_bounds__(256) void bn_apply_kernel(
    float* __restrict__ Y, const float* __restrict__ stats,
    const float* __restrict__ g, const float* __restrict__ bb,
    int Co, int HW, int total)
{
    int idx = blockIdx.x * 256 + threadIdx.x;
    if (idx >= total) return;
    int c = (idx / HW) % Co;
    float mean = stats[c * 2], var = stats[c * 2 + 1];
    float sc = g[c] / sqrtf(var + 1e-5f);
    float sf = bb[c] - mean * sc;
    float v = Y[idx] * sc + sf;
    Y[idx] = v > 0.f ? v : 0.f;
}

// ---------------------------------------------------------------------------
// Host orchestration. Workspace footprint ~29.5 MB, same layout as round 2
// (verified in-bounds). Scratch Q reuse by lifetime: x1=Q (L1-2), x3=Q (L3-4),
// x4=Q (L5-6), x41=Q+512K (L6-7), x5=Q+1M (L7-8).
// ---------------------------------------------------------------------------
extern "C" void kernel_launch(void* const* d_in, const int* in_sizes, int n_in,
                              void* d_out, int out_size, void* d_ws, size_t ws_size,
                              hipStream_t stream)
{
    const int B = 4;
    float* ws = (float*)d_ws;
    size_t off = 0;
    auto alloc = [&](size_t n) -> float* {
        float* p = ws + off;
        off += (n + 63) & ~(size_t)63;
        return p;
    };

    float* stats = alloc(512);

    static const int kH[8]  = {256, 128, 64, 32, 32, 16, 32, 64};
    static const int kW[8]  = {512, 256, 128, 64, 64, 32, 64, 128};
    static const int kK[8]  = {7, 5, 5, 3, 3, 3, 3, 3};
    static const int kSt[8] = {2, 2, 2, 1, 2, 1, 1, 1};
    float* rows_g[8]; float* dcol_g[8];
    for (int i = 0; i < 8; i++) {
        int Ho = kH[i] / kSt[i];
        int K2 = kK[i] * kK[i];
        rows_g[i] = alloc((size_t)Ho * K2);
        dcol_g[i] = alloc((size_t)Ho * K2);
    }

    float* x2  = alloc((size_t)B * 64  * 64 * 128);   // persists L2..L8
    float* x31 = alloc((size_t)B * 128 * 32 * 64);    // persists L4..L7
    float* Q   = alloc((size_t)B * 32  * 128 * 256);  // shared scratch
    float* x1  = Q;
    float* x3  = Q;
    float* x4  = Q;
    float* x41 = Q + (size_t)B * 256 * 16 * 32;
    float* x5  = Q + 2 * (size_t)B * 256 * 16 * 32;
    (void)ws_size; (void)in_sizes; (void)n_in; (void)out_size;

    struct LCfg { const float *s1, *s2; int C1, C2, up; float delta; int widx, Cout; float* Y; };
    const float* input = (const float*)d_in[0];
    LCfg L[8] = {
        { input, nullptr,   6,   0, 0, PI_F / 32.f,  1,  32, x1  },
        { x1,    nullptr,  32,   0, 0, PI_F / 16.f,  5,  64, x2  },
        { x2,    nullptr,  64,   0, 0, PI_F / 4.f,   9, 128, x3  },
        { x3,    nullptr, 128,   0, 0, PI_F / 4.f,  13, 128, x31 },
        { x31,   nullptr, 128,   0, 0, PI_F / 2.f,  17, 256, x4  },
        { x4,    nullptr, 256,   0, 0, PI_F / 2.f,  21, 256, x41 },
        { x41,   x31,     256, 128, 1, PI_F / 4.f,  25, 256, x5  },
        { x5,    x2,      256,  64, 1, PI_F / 8.f,  29, 128, (float*)d_out },
    };

    for (int i = 0; i < 8; i++) {
        const LCfg& c = L[i];
        int H = kH[i], W = kW[i], k = kK[i], st = kSt[i];
        int Ho = H / st, Wo = W / st;
        int K2 = k * k;
        int K  = (c.C1 + c.C2) * K2;
        int HW = Ho * Wo;
        int N  = B * HW;
        int lWo = __builtin_ctz(Wo), lHo = __builtin_ctz(Ho);
        const float* Wt   = (const float*)d_in[c.widx];
        const float* bias = (const float*)d_in[c.widx + 1];
        const float* gam  = (const float*)d_in[c.widx + 2];
        const float* bet  = (const float*)d_in[c.widx + 3];

        int gn = Ho * K2;
        make_grid_kernel<<<dim3((gn + 255) / 256), dim3(256), 0, stream>>>(
            rows_g[i], dcol_g[i], Ho, K2, k, H, W, st, c.delta);

        dim3 mgrid(N / BNT, (c.Cout + BMT - 1) / BMT);
        sconv_mfma_kernel<<<mgrid, dim3(256), 0, stream>>>(
            Wt, bias, c.s1, c.s2, c.C1, c.C2, H, W, c.up,
            rows_g[i], dcol_g[i], K2, st, lWo, lHo,
            c.Y, c.Cout, K, N);

        bn_stats_kernel<<<dim3(c.Cout), dim3(256), 0, stream>>>(c.Y, stats, c.Cout, HW, B);
        int total = B * c.Cout * HW;
        bn_apply_kernel<<<dim3((total + 255) / 256), dim3(256), 0, stream>>>(
            c.Y, stats, gam, bet, c.Cout, HW, total);
    }
}

// Round 5
// 2195.124 us; speedup vs baseline: 1.9705x; 1.9705x over previous
//
#include <hip/hip_runtime.h>
#include <cstddef>
#include <cstdint>

#define PI_F 3.14159265358979323846f

typedef __attribute__((ext_vector_type(8))) short short8;   // 8 bf16 = 4 VGPRs
typedef __attribute__((ext_vector_type(4))) short short4v;  // 8B LDS store
typedef __attribute__((ext_vector_type(4))) float floatx4;  // MFMA acc

__device__ __forceinline__ short f2bf(float f) {
    union { float f; unsigned u; } v; v.f = f;
    unsigned r = v.u + 0x7FFFu + ((v.u >> 16) & 1u);   // RNE
    return (short)(r >> 16);
}

// ---------------------------------------------------------------------------
// Fused spherical-conv GEMM, bf16 MFMA, latency-optimized.
//   Y[b][m][ho][wo] = sum_k A[m][k] * patch(n,k) + bias[m]
// Block tile 64x64, BK=32, 256 threads = 4 waves (2x2), each wave 32x32 via
// 2x2 v_mfma_f32_16x16x32_bf16. Per-block LDS table holds per-(ho,tap)
// precomputed {fr, dcol, r0i, r1i} (trig hoisted out of the K-loop).
// Gather loads coalesced: lane = consecutive wo -> consecutive columns.
// Channels < C1 sample src1 (optionally nearest-2x upsampled via >>up1);
// channels >= C1 sample src2 -> fuses up2+concat of the skip connections.
// NOTE: ragged-K guard MUST wrap the loads (layer 1: K=294, src2=nullptr;
// out-of-range slots would compute c>=C1 and deref null) — round-4 crash.
// ---------------------------------------------------------------------------
#define BMT 64
#define BNT 64
#define BKT 32
#define LDK 40

__global__ __launch_bounds__(256) void sconv_mfma_kernel(
    const float* __restrict__ A, const float* __restrict__ bias,
    const float* __restrict__ src1, const float* __restrict__ src2,
    int C1, int C2, int H, int W, int up1,
    int K2, int ksz, int stride, int lWo, int lHo, float delta,
    float* __restrict__ Y, int M, int K, int N)
{
    __shared__ short As[BMT][LDK];
    __shared__ short Bs[BNT][LDK];
    __shared__ float4 tab[64];          // max nHo*K2 = 49 over all layers

    const int tid = threadIdx.x;
    const int n0  = blockIdx.x * BNT;
    const int m0  = blockIdx.y * BMT;
    const int Wo  = 1 << lWo;
    const int Ho  = 1 << lHo;
    const int HW  = 1 << (lWo + lHo);

    // ---- per-block grid table: (hoLocal, tap) -> {fr, dcol, r0i, r1i} ----
    const int nHo  = (lWo >= 6) ? 1 : (BNT >> lWo);
    const int nEnt = nHo * K2;
    const int hoBase = (n0 >> lWo) & (Ho - 1);
    if (tid < nEnt) {
        int hoL = tid / K2;
        int i   = tid - hoL * K2;
        int ho_g = hoBase + hoL;
        int jy = i / ksz, jx = i - jy * ksz;
        float halfk = (ksz - 1) * 0.5f;
        float yy = tanf(delta / (float)ksz * ((float)jy - halfk));
        float xx = tanf(delta / (float)ksz * ((float)jx - halfk));
        float rho = sqrtf(xx * xx + yy * yy);
        float rho_s = (rho == 0.f) ? 1.f : rho;
        float nu = atanf(rho);
        float lat0 = PI_F * 0.5f - ((float)(ho_g * stride) + 0.5f) * (PI_F / (float)H);
        float sl = sinf(lat0), cl = cosf(lat0);
        float sn = sinf(nu),  cn = cosf(nu);
        float arg = cn * sl + (yy / rho_s) * sn * cl;
        arg = fminf(1.f, fmaxf(-1.f, arg));
        float lat = asinf(arg);
        float dlon = atan2f(xx * sn, rho * cl * cn - yy * sl * sn);
        float row = (PI_F * 0.5f - lat) / PI_F * (float)H - 0.5f;
        float dcol = dlon / (2.f * PI_F) * (float)W;
        float r0f = floorf(row);
        float fr = row - r0f;
        int r0 = (int)r0f;
        int r0i = min(max(r0, 0), H - 1);
        int r1i = min(max(r0 + 1, 0), H - 1);
        tab[tid] = make_float4(fr, dcol, __int_as_float(r0i), __int_as_float(r1i));
    }

    // ---- A staging map: 8 lanes x 4k chunks, rows amr and amr+32 ----
    const int akq = (tid & 7) * 4;      // k offset within tile
    const int amr = tid >> 3;           // 0..31

    // ---- B staging map: lane nn (coalesced wo), kslot*8 + j samples ----
    const int nn    = tid & 63;
    const int kslot = tid >> 6;         // wave-uniform
    const int n_s  = n0 + nn;
    const int wo_s = n_s & (Wo - 1);
    const int hoL_s = nn >> lWo;        // ho local within block (0 if Wo>=64)
    const int b_s  = n_s >> (lWo + lHo);
    const int tabBase = hoL_s * K2;
    const float wo_px = (float)(wo_s * stride);
    const int Hs = H >> up1, Ws = W >> up1;
    const int plane1 = Hs * Ws;
    const int plane2 = H * W;
    const float* base1 = src1 + (size_t)b_s * C1 * plane1;
    const float* base2 = src2 ? (src2 + (size_t)b_s * C2 * plane2) : (const float*)0;

    // ---- wave/lane decomposition for MFMA ----
    const int wave = tid >> 6;
    const int wm   = (wave & 1) * 32;
    const int wn   = (wave >> 1) * 32;
    const int lane = tid & 63;
    const int l16  = lane & 15;
    const int quad = lane >> 4;

    floatx4 acc[2][2];
#pragma unroll
    for (int i = 0; i < 2; i++)
#pragma unroll
        for (int j = 0; j < 2; j++)
            acc[i][j] = (floatx4){0.f, 0.f, 0.f, 0.f};

    __syncthreads();   // table ready

    for (int k0 = 0; k0 < K; k0 += BKT) {
        // ---- A tile: fp32 -> bf16 ----
        {
            const bool fast = ((K & 3) == 0) && (k0 + BKT <= K);
#pragma unroll
            for (int half = 0; half < 2; half++) {
                int m = m0 + amr + half * 32;
                short4v s4;
                if (fast && m < M) {
                    const float4 av = *(const float4*)(A + (size_t)m * K + k0 + akq);
                    s4.x = f2bf(av.x); s4.y = f2bf(av.y);
                    s4.z = f2bf(av.z); s4.w = f2bf(av.w);
                } else {
                    float tv[4];
#pragma unroll
                    for (int t = 0; t < 4; t++) {
                        int k = k0 + akq + t;
                        tv[t] = (m < M && k < K) ? A[(size_t)m * K + k] : 0.f;
                    }
                    s4.x = f2bf(tv[0]); s4.y = f2bf(tv[1]);
                    s4.z = f2bf(tv[2]); s4.w = f2bf(tv[3]);
                }
                *(short4v*)&As[amr + half * 32][akq] = s4;
            }
        }
        // ---- B tile: bilinear gather via LDS table ----
        {
            int kStart = k0 + kslot * 8;
            int c   = (int)((unsigned)kStart / (unsigned)K2);
            int tap = kStart - c * K2;
            short t8[8];
#pragma unroll
            for (int j = 0; j < 8; j++) {
                float v = 0.f;
                if (kStart + j < K) {   // guard BEFORE loads (layer-1 ragged K)
                    float4 e = tab[tabBase + tap];
                    float fr = e.x;
                    float col = wo_px + e.y;
                    int r0i = __float_as_int(e.z);
                    int r1i = __float_as_int(e.w);
                    float cf = floorf(col);
                    float fc = col - cf;
                    int c0 = ((int)cf) & (W - 1);
                    int c1 = (c0 + 1) & (W - 1);
                    float v00, v01, v10, v11;
                    if (c < C1) {
                        const float* p = base1 + (size_t)c * plane1;
                        int ra = (r0i >> up1) * Ws, rb = (r1i >> up1) * Ws;
                        int ca = c0 >> up1, cb = c1 >> up1;
                        v00 = p[ra + ca]; v01 = p[ra + cb];
                        v10 = p[rb + ca]; v11 = p[rb + cb];
                    } else {
                        const float* p = base2 + (size_t)(c - C1) * plane2;
                        int ra = r0i * W, rb = r1i * W;
                        v00 = p[ra + c0]; v01 = p[ra + c1];
                        v10 = p[rb + c0]; v11 = p[rb + c1];
                    }
                    v = (1.f - fr) * ((1.f - fc) * v00 + fc * v01)
                      +        fr  * ((1.f - fc) * v10 + fc * v11);
                }
                t8[j] = f2bf(v);
                if (++tap == K2) { tap = 0; ++c; }
            }
            *(short8*)&Bs[nn][kslot * 8] = *(short8*)&t8[0];
        }
        __syncthreads();

        short8 af[2], bfrag[2];
#pragma unroll
        for (int i = 0; i < 2; i++)
            af[i] = *(const short8*)&As[wm + i * 16 + l16][quad * 8];
#pragma unroll
        for (int j = 0; j < 2; j++)
            bfrag[j] = *(const short8*)&Bs[wn + j * 16 + l16][quad * 8];
#pragma unroll
        for (int i = 0; i < 2; i++)
#pragma unroll
            for (int j = 0; j < 2; j++)
                acc[i][j] = __builtin_amdgcn_mfma_f32_16x16x32_bf16(
                    af[i], bfrag[j], acc[i][j], 0, 0, 0);
        __syncthreads();
    }

    // ---- epilogue: C/D layout col=lane&15, row=quad*4+reg ----
#pragma unroll
    for (int i = 0; i < 2; i++) {
#pragma unroll
        for (int j = 0; j < 2; j++) {
            const int n = n0 + wn + j * 16 + l16;
            const int wo = n & (Wo - 1);
            const int r  = n >> lWo;
            const int ho = r & (Ho - 1);
            const int b_ = r >> lHo;
#pragma unroll
            for (int rr = 0; rr < 4; rr++) {
                const int m = m0 + wm + i * 16 + quad * 4 + rr;
                if (m < M)
                    Y[((size_t)b_ * M + m) * HW + (ho << lWo) + wo] =
                        acc[i][j][rr] + bias[m];
            }
        }
    }
}

// ---------------------------------------------------------------------------
// BN stats: one block per channel; mean + biased var over (B, Ho, Wo).
// ---------------------------------------------------------------------------
__global__ __launch_bounds__(256) void bn_stats_kernel(
    const float* __restrict__ Y, float* __restrict__ stats,
    int Co, int HW, int B)
{
    int co = blockIdx.x;
    int tid = threadIdx.x;
    int Nt = B * HW;
    double s = 0.0, s2 = 0.0;
    for (int idx = tid; idx < Nt; idx += 256) {
        int b = idx / HW; int sp = idx - b * HW;
        float v = Y[((size_t)b * Co + co) * HW + sp];
        s += v; s2 += (double)v * v;
    }
    __shared__ double sh_s[256], sh_s2[256];
    sh_s[tid] = s; sh_s2[tid] = s2;
    __syncthreads();
    for (int off = 128; off > 0; off >>= 1) {
        if (tid < off) { sh_s[tid] += sh_s[tid + off]; sh_s2[tid] += sh_s2[tid + off]; }
        __syncthreads();
    }
    if (tid == 0) {
        double mean = sh_s[0] / Nt;
        double var = sh_s2[0] / Nt - mean * mean;
        if (var < 0.0) var = 0.0;
        stats[co * 2]     = (float)mean;
        stats[co * 2 + 1] = (float)var;
    }
}

__global__ __launch_bounds__(256) void bn_apply_kernel(
    float* __restrict__ Y, const float* __restrict__ stats,
    const float* __restrict__ g, const float* __restrict__ bb,
    int Co, int HW, int total)
{
    int idx = blockIdx.x * 256 + threadIdx.x;
    if (idx >= total) return;
    int c = (idx / HW) % Co;
    float mean = stats[c * 2], var = stats[c * 2 + 1];
    float sc = g[c] / sqrtf(var + 1e-5f);
    float sf = bb[c] - mean * sc;
    float v = Y[idx] * sc + sf;
    Y[idx] = v > 0.f ? v : 0.f;
}

// ---------------------------------------------------------------------------
// Host orchestration. Workspace ~29.5 MB, layout proven in rounds 2-3.
// Scratch Q reuse by lifetime: x1=Q (L1-2), x3=Q (L3-4), x4=Q (L5-6),
// x41=Q+512K (L6-7), x5=Q+1M (L7-8).
// ---------------------------------------------------------------------------
extern "C" void kernel_launch(void* const* d_in, const int* in_sizes, int n_in,
                              void* d_out, int out_size, void* d_ws, size_t ws_size,
                              hipStream_t stream)
{
    const int B = 4;
    float* ws = (float*)d_ws;
    size_t off = 0;
    auto alloc = [&](size_t n) -> float* {
        float* p = ws + off;
        off += (n + 63) & ~(size_t)63;
        return p;
    };

    float* stats = alloc(512);
    float* x2  = alloc((size_t)B * 64  * 64 * 128);   // persists L2..L8
    float* x31 = alloc((size_t)B * 128 * 32 * 64);    // persists L4..L7
    float* Q   = alloc((size_t)B * 32  * 128 * 256);  // shared scratch
    float* x1  = Q;
    float* x3  = Q;
    float* x4  = Q;
    float* x41 = Q + (size_t)B * 256 * 16 * 32;
    float* x5  = Q + 2 * (size_t)B * 256 * 16 * 32;
    (void)ws_size; (void)in_sizes; (void)n_in; (void)out_size;

    static const int kH[8]  = {256, 128, 64, 32, 32, 16, 32, 64};
    static const int kW[8]  = {512, 256, 128, 64, 64, 32, 64, 128};
    static const int kK[8]  = {7, 5, 5, 3, 3, 3, 3, 3};
    static const int kSt[8] = {2, 2, 2, 1, 2, 1, 1, 1};

    struct LCfg { const float *s1, *s2; int C1, C2, up; float delta; int widx, Cout; float* Y; };
    const float* input = (const float*)d_in[0];
    LCfg L[8] = {
        { input, nullptr,   6,   0, 0, PI_F / 32.f,  1,  32, x1  },
        { x1,    nullptr,  32,   0, 0, PI_F / 16.f,  5,  64, x2  },
        { x2,    nullptr,  64,   0, 0, PI_F / 4.f,   9, 128, x3  },
        { x3,    nullptr, 128,   0, 0, PI_F / 4.f,  13, 128, x31 },
        { x31,   nullptr, 128,   0, 0, PI_F / 2.f,  17, 256, x4  },
        { x4,    nullptr, 256,   0, 0, PI_F / 2.f,  21, 256, x41 },
        { x41,   x31,     256, 128, 1, PI_F / 4.f,  25, 256, x5  },
        { x5,    x2,      256,  64, 1, PI_F / 8.f,  29, 128, (float*)d_out },
    };

    for (int i = 0; i < 8; i++) {
        const LCfg& c = L[i];
        int H = kH[i], W = kW[i], k = kK[i], st = kSt[i];
        int Ho = H / st, Wo = W / st;
        int K2 = k * k;
        int K  = (c.C1 + c.C2) * K2;
        int HW = Ho * Wo;
        int N  = B * HW;
        int lWo = __builtin_ctz(Wo), lHo = __builtin_ctz(Ho);
        const float* Wt   = (const float*)d_in[c.widx];
        const float* bias = (const float*)d_in[c.widx + 1];
        const float* gam  = (const float*)d_in[c.widx + 2];
        const float* bet  = (const float*)d_in[c.widx + 3];

        dim3 mgrid(N / BNT, (c.Cout + BMT - 1) / BMT);
        sconv_mfma_kernel<<<mgrid, dim3(256), 0, stream>>>(
            Wt, bias, c.s1, c.s2, c.C1, c.C2, H, W, c.up,
            K2, k, st, lWo, lHo, c.delta,
            c.Y, c.Cout, K, N);

        bn_stats_kernel<<<dim3(c.Cout), dim3(256), 0, stream>>>(c.Y, stats, c.Cout, HW, B);
        int total = B * c.Cout * HW;
        bn_apply_kernel<<<dim3((total + 255) / 256), dim3(256), 0, stream>>>(
            c.Y, stats, gam, bet, c.Cout, HW, total);
    }
}

// Round 6
// 1599.601 us; speedup vs baseline: 2.7041x; 1.3723x over previous
//
#include <hip/hip_runtime.h>
#include <cstddef>
#include <cstdint>

#define PI_F 3.14159265358979323846f
#define SPLIT 8

typedef __attribute__((ext_vector_type(8))) short short8;   // 8 bf16 = 4 VGPRs
typedef __attribute__((ext_vector_type(4))) float floatx4;  // MFMA acc

__device__ __forceinline__ short f2bf(float f) {
    union { float f; unsigned u; } v; v.f = f;
    unsigned r = v.u + 0x7FFFu + ((v.u >> 16) & 1u);   // RNE
    return (short)(r >> 16);
}

// ---------------------------------------------------------------------------
// Weight transpose+convert: Abf[m][k'] = bf16(A[m][c*K2 + tap]),
// k' = tap*Cp + c. Zero-pads m in [M,Mpad), c in [C,Cp), tap in [K2, ...).
// Runs every call (weights restored per replay).
// ---------------------------------------------------------------------------
__global__ __launch_bounds__(256) void wtrans_kernel(
    const float* __restrict__ A, short* __restrict__ Abf,
    int M, int Mpad, int K2, int C, int Cp, int Kp, int Korig)
{
    int idx = blockIdx.x * 256 + threadIdx.x;
    if (idx >= Mpad * Kp) return;
    int m = idx / Kp;
    int k = idx - m * Kp;
    int tap = (unsigned)k / (unsigned)Cp;
    int c   = k - tap * Cp;
    float v = 0.f;
    if (m < M && tap < K2 && c < C) v = A[(size_t)m * Korig + c * K2 + tap];
    Abf[idx] = f2bf(v);
}

// ---------------------------------------------------------------------------
// Fused spherical-conv GEMM, bf16 MFMA, channel-innermost K (k' = tap*Cp+c).
// Block tile 64x64, BK=32, 256 threads = 4 waves (2x2), each wave 32x32 via
// 2x2 v_mfma_f32_16x16x32_bf16.
// - A fragments: direct global short8 loads from pre-transposed Abf (L1-hot).
// - B tile: per K-tile each thread owns ONE tap and 8 consecutive channels:
//   coords + bilinear weights + 4 corner indices computed once, inner loop is
//   4 loads + 4 FMA + f2bf per channel (idx += plane).
// - Per-block LDS table: (hoLocal, tap) -> {fr, dcol, r0i, r1i} (trig once).
// - Channels < C1 sample src1 (>>up1 nearest-2x upsample); >= C1 sample src2
//   (fuses up2+concat). Chunks never straddle C1 (all C multiples of 8).
// - Ragged/pad K (L1): tap clamped (finite B), Abf=0 there; guard c<Ctot
//   wraps the loads (src2 may be null).
// ---------------------------------------------------------------------------
#define BMT 64
#define BNT 64
#define BKT 32
#define LDK 40

__global__ __launch_bounds__(256) void sconv_mfma_kernel(
    const short* __restrict__ Abf, const float* __restrict__ bias,
    const float* __restrict__ src1, const float* __restrict__ src2,
    int C1, int Ctot, int Cp, int H, int W, int up1,
    int K2, int ksz, int stride, int lWo, int lHo, float delta,
    float* __restrict__ Y, int M, int Kp, int N)
{
    __shared__ short Bs[BNT][LDK];
    __shared__ float4 tab[64];          // max nHo*K2 = 49 over all layers

    const int tid = threadIdx.x;
    const int n0  = blockIdx.x * BNT;
    const int m0  = blockIdx.y * BMT;
    const int Wo  = 1 << lWo;
    const int Ho  = 1 << lHo;
    const int HW  = 1 << (lWo + lHo);

    // ---- per-block grid table ----
    const int nHo  = (lWo >= 6) ? 1 : (BNT >> lWo);
    const int nEnt = nHo * K2;
    const int hoBase = (n0 >> lWo) & (Ho - 1);
    if (tid < nEnt) {
        int hoL = tid / K2;
        int i   = tid - hoL * K2;
        int ho_g = hoBase + hoL;
        int jy = i / ksz, jx = i - jy * ksz;
        float halfk = (ksz - 1) * 0.5f;
        float yy = tanf(delta / (float)ksz * ((float)jy - halfk));
        float xx = tanf(delta / (float)ksz * ((float)jx - halfk));
        float rho = sqrtf(xx * xx + yy * yy);
        float rho_s = (rho == 0.f) ? 1.f : rho;
        float nu = atanf(rho);
        float lat0 = PI_F * 0.5f - ((float)(ho_g * stride) + 0.5f) * (PI_F / (float)H);
        float sl = sinf(lat0), cl = cosf(lat0);
        float sn = sinf(nu),  cn = cosf(nu);
        float arg = cn * sl + (yy / rho_s) * sn * cl;
        arg = fminf(1.f, fmaxf(-1.f, arg));
        float lat = asinf(arg);
        float dlon = atan2f(xx * sn, rho * cl * cn - yy * sl * sn);
        float row = (PI_F * 0.5f - lat) / PI_F * (float)H - 0.5f;
        float dcol = dlon / (2.f * PI_F) * (float)W;
        float r0f = floorf(row);
        float fr = row - r0f;
        int r0 = (int)r0f;
        int r0i = min(max(r0, 0), H - 1);
        int r1i = min(max(r0 + 1, 0), H - 1);
        tab[tid] = make_float4(fr, dcol, __int_as_float(r0i), __int_as_float(r1i));
    }

    // ---- B staging geometry (lane nn = coalesced wo) ----
    const int nn    = tid & 63;
    const int kslot = tid >> 6;         // wave-uniform
    const int n_s  = n0 + nn;
    const int wo_s = n_s & (Wo - 1);
    const int hoL_s = nn >> lWo;
    const int b_s  = n_s >> (lWo + lHo);   // block-uniform (HW multiple of 64)
    const int tabBase = hoL_s * K2;
    const float wo_px = (float)(wo_s * stride);
    const int Hs = H >> up1, Ws = W >> up1;
    const int plane1 = Hs * Ws;
    const int plane2 = H * W;
    const unsigned boff1 = (unsigned)(b_s * C1 * plane1);
    const unsigned boff2 = (unsigned)(b_s * (Ctot - C1) * plane2);

    // ---- per-K-tile (tap, cb) iteration state: chunk = one tap, 8 channels
    const bool smallC = (Cp < 32);      // layer 1 only (Cp=8)
    int tap = smallC ? kslot : 0;
    int cb  = smallC ? 0 : kslot * 8;
    const int dtap = smallC ? (32 / Cp) : 0;

    // ---- wave/lane decomposition for MFMA ----
    const int wave = tid >> 6;
    const int wm   = (wave & 1) * 32;
    const int wn   = (wave >> 1) * 32;
    const int lane = tid & 63;
    const int l16  = lane & 15;
    const int quad = lane >> 4;

    // A fragment row pointers (direct global loads)
    const short* pA0 = Abf + (size_t)(m0 + wm + l16) * Kp + quad * 8;
    const short* pA1 = pA0 + (size_t)16 * Kp;

    floatx4 acc[2][2];
#pragma unroll
    for (int i = 0; i < 2; i++)
#pragma unroll
        for (int j = 0; j < 2; j++)
            acc[i][j] = (floatx4){0.f, 0.f, 0.f, 0.f};

    __syncthreads();   // table ready

    for (int k0 = 0; k0 < Kp; k0 += BKT) {
        // ---- B tile: one tap, 8 channels ----
        {
            const int tapc = min(tap, K2 - 1);       // clamp for L1 pad region
            const float4 e = tab[tabBase + tapc];
            const float fr = e.x;
            const float col = wo_px + e.y;
            const int r0i = __float_as_int(e.z);
            const int r1i = __float_as_int(e.w);
            const float cf = floorf(col);
            const float fc = col - cf;
            const int c0 = ((int)cf) & (W - 1);
            const int c1 = (c0 + 1) & (W - 1);
            const float w00 = (1.f - fr) * (1.f - fc);
            const float w01 = (1.f - fr) * fc;
            const float w10 = fr * (1.f - fc);
            const float w11 = fr * fc;

            const float* src; unsigned i00, i01, i10, i11, plane;
            if (cb < C1) {               // wave-uniform branch
                const int ra = (r0i >> up1) * Ws, rb = (r1i >> up1) * Ws;
                const int ca = c0 >> up1, cx = c1 >> up1;
                const unsigned base = boff1 + (unsigned)cb * plane1;
                i00 = base + ra + ca; i01 = base + ra + cx;
                i10 = base + rb + ca; i11 = base + rb + cx;
                plane = plane1; src = src1;
            } else {
                const int ra = r0i * W, rb = r1i * W;
                const unsigned base = boff2 + (unsigned)(cb - C1) * plane2;
                i00 = base + ra + c0; i01 = base + ra + c1;
                i10 = base + rb + c0; i11 = base + rb + c1;
                plane = plane2; src = src2;
            }
            short t8[8];
#pragma unroll
            for (int j = 0; j < 8; j++) {
                float v = 0.f;
                if (cb + j < Ctot) {     // guard BEFORE loads (L1: Ctot=6)
                    v = w00 * src[i00] + w01 * src[i01]
                      + w10 * src[i10] + w11 * src[i11];
                }
                t8[j] = f2bf(v);
                i00 += plane; i01 += plane; i10 += plane; i11 += plane;
            }
            *(short8*)&Bs[nn][kslot * 8] = *(short8*)&t8[0];
        }
        __syncthreads();

        const short8 af0 = *(const short8*)(pA0 + k0);
        const short8 af1 = *(const short8*)(pA1 + k0);
        short8 bfrag[2];
#pragma unroll
        for (int j = 0; j < 2; j++)
            bfrag[j] = *(const short8*)&Bs[wn + j * 16 + l16][quad * 8];
        acc[0][0] = __builtin_amdgcn_mfma_f32_16x16x32_bf16(af0, bfrag[0], acc[0][0], 0, 0, 0);
        acc[0][1] = __builtin_amdgcn_mfma_f32_16x16x32_bf16(af0, bfrag[1], acc[0][1], 0, 0, 0);
        acc[1][0] = __builtin_amdgcn_mfma_f32_16x16x32_bf16(af1, bfrag[0], acc[1][0], 0, 0, 0);
        acc[1][1] = __builtin_amdgcn_mfma_f32_16x16x32_bf16(af1, bfrag[1], acc[1][1], 0, 0, 0);
        __syncthreads();

        // advance (tap, cb)
        if (smallC) { tap += dtap; }
        else { cb += 32; if (cb >= Cp) { cb -= Cp; tap++; } }
    }

    // ---- epilogue: C/D layout col=lane&15, row=quad*4+reg ----
#pragma unroll
    for (int i = 0; i < 2; i++) {
#pragma unroll
        for (int j = 0; j < 2; j++) {
            const int n = n0 + wn + j * 16 + l16;
            const int wo = n & (Wo - 1);
            const int r  = n >> lWo;
            const int ho = r & (Ho - 1);
            const int b_ = r >> lHo;
#pragma unroll
            for (int rr = 0; rr < 4; rr++) {
                const int m = m0 + wm + i * 16 + quad * 4 + rr;
                if (m < M)
                    Y[((size_t)b_ * M + m) * HW + (ho << lWo) + wo] =
                        acc[i][j][rr] + bias[m];
            }
        }
    }
}

// ---------------------------------------------------------------------------
// BN stats, split 8-way per channel: partial mean/sq sums (double).
// ---------------------------------------------------------------------------
__global__ __launch_bounds__(256) void bn_stats_part_kernel(
    const float* __restrict__ Y, double* __restrict__ part,
    int Co, int HW, int B)
{
    int co = blockIdx.x;
    int sp = blockIdx.y;
    int tid = threadIdx.x;
    int Nt = B * HW;
    int len = (Nt + SPLIT - 1) / SPLIT;
    int start = sp * len;
    int end = min(Nt, start + len);
    double s = 0.0, s2 = 0.0;
    for (int idx = start + tid; idx < end; idx += 256) {
        int b = idx / HW; int o = idx - b * HW;
        float v = Y[((size_t)b * Co + co) * HW + o];
        s += v; s2 += (double)v * v;
    }
    __shared__ double sh_s[256], sh_s2[256];
    sh_s[tid] = s; sh_s2[tid] = s2;
    __syncthreads();
    for (int off = 128; off > 0; off >>= 1) {
        if (tid < off) { sh_s[tid] += sh_s[tid + off]; sh_s2[tid] += sh_s2[tid + off]; }
        __syncthreads();
    }
    if (tid == 0) {
        part[(co * SPLIT + sp) * 2]     = sh_s[0];
        part[(co * SPLIT + sp) * 2 + 1] = sh_s2[0];
    }
}

// Finalize (per-block, channel uniform since HW>=512) + normalize + ReLU.
__global__ __launch_bounds__(256) void bn_apply_kernel(
    float* __restrict__ Y, const double* __restrict__ part,
    const float* __restrict__ g, const float* __restrict__ bb,
    int Co, int HW, int B, int total)
{
    int idx = blockIdx.x * 256 + threadIdx.x;
    int c = (idx / HW) % Co;           // uniform within block (256 | HW)
    __shared__ float s_sc, s_sf;
    if (threadIdx.x == 0) {
        double s = 0.0, s2 = 0.0;
        for (int p = 0; p < SPLIT; p++) {
            s  += part[(c * SPLIT + p) * 2];
            s2 += part[(c * SPLIT + p) * 2 + 1];
        }
        int Nt = B * HW;
        double mean = s / Nt;
        double var = s2 / Nt - mean * mean;
        if (var < 0.0) var = 0.0;
        float sc = g[c] / sqrtf((float)var + 1e-5f);
        s_sc = sc;
        s_sf = bb[c] - (float)mean * sc;
    }
    __syncthreads();
    if (idx >= total) return;
    float v = Y[idx] * s_sc + s_sf;
    Y[idx] = v > 0.f ? v : 0.f;
}

// ---------------------------------------------------------------------------
// Host orchestration. Workspace ~35 MB: partials 32KB + activations 29.4MB +
// Abf 5.1MB. Scratch Q reuse by lifetime: x1=Q (L1-2), x3=Q (L3-4),
// x4=Q (L5-6), x41=Q+512K (L6-7), x5=Q+1M (L7-8).
// ---------------------------------------------------------------------------
extern "C" void kernel_launch(void* const* d_in, const int* in_sizes, int n_in,
                              void* d_out, int out_size, void* d_ws, size_t ws_size,
                              hipStream_t stream)
{
    const int B = 4;
    char* ws = (char*)d_ws;
    size_t off = 0;
    auto allocb = [&](size_t bytes) -> void* {
        void* p = ws + off;
        off = (off + bytes + 255) & ~(size_t)255;
        return p;
    };

    double* part = (double*)allocb(256 * SPLIT * 2 * sizeof(double));
    float* x2  = (float*)allocb((size_t)B * 64  * 64 * 128 * 4);
    float* x31 = (float*)allocb((size_t)B * 128 * 32 * 64 * 4);
    float* Q   = (float*)allocb((size_t)B * 32  * 128 * 256 * 4);
    float* x1  = Q;
    float* x3  = Q;
    float* x4  = Q;
    float* x41 = Q + (size_t)B * 256 * 16 * 32;
    float* x5  = Q + 2 * (size_t)B * 256 * 16 * 32;

    //                      1     2     3    31     4    41     5     6
    static const int kH[8]  = {256, 128,  64,  32,  32,  16,  32,  64};
    static const int kW[8]  = {512, 256, 128,  64,  64,  32,  64, 128};
    static const int kK[8]  = {  7,   5,   5,   3,   3,   3,   3,   3};
    static const int kSt[8] = {  2,   2,   2,   1,   2,   1,   1,   1};
    static const int kC[8]  = {  6,  32,  64, 128, 128, 256, 384, 320};
    static const int kM[8]  = { 32,  64, 128, 128, 256, 256, 256, 128};

    // per-layer padded dims + Abf buffers
    int Cp_[8], Kp_[8], Mpad_[8];
    short* Abf[8];
    for (int i = 0; i < 8; i++) {
        int K2 = kK[i] * kK[i];
        int Cp = (kC[i] < 8) ? 8 : kC[i];
        int Kp = (K2 * Cp + 31) & ~31;
        int Mpad = (kM[i] + 63) & ~63;
        Cp_[i] = Cp; Kp_[i] = Kp; Mpad_[i] = Mpad;
        Abf[i] = (short*)allocb((size_t)Mpad * Kp * sizeof(short));
    }
    (void)ws_size; (void)in_sizes; (void)n_in; (void)out_size;

    struct LCfg { const float *s1, *s2; int C1, up; float delta; int widx; float* Y; };
    const float* input = (const float*)d_in[0];
    LCfg L[8] = {
        { input, nullptr,   6, 0, PI_F / 32.f,  1, x1  },
        { x1,    nullptr,  32, 0, PI_F / 16.f,  5, x2  },
        { x2,    nullptr,  64, 0, PI_F / 4.f,   9, x3  },
        { x3,    nullptr, 128, 0, PI_F / 4.f,  13, x31 },
        { x31,   nullptr, 128, 0, PI_F / 2.f,  17, x4  },
        { x4,    nullptr, 256, 0, PI_F / 2.f,  21, x41 },
        { x41,   x31,     256, 1, PI_F / 4.f,  25, x5  },
        { x5,    x2,      256, 1, PI_F / 8.f,  29, (float*)d_out },
    };

    for (int i = 0; i < 8; i++) {
        const LCfg& c = L[i];
        int H = kH[i], W = kW[i], k = kK[i], st = kSt[i];
        int Ho = H / st, Wo = W / st;
        int K2 = k * k;
        int C  = kC[i], M = kM[i];
        int HW = Ho * Wo;
        int N  = B * HW;
        int lWo = __builtin_ctz(Wo), lHo = __builtin_ctz(Ho);
        const float* Wt   = (const float*)d_in[c.widx];
        const float* bias = (const float*)d_in[c.widx + 1];
        const float* gam  = (const float*)d_in[c.widx + 2];
        const float* bet  = (const float*)d_in[c.widx + 3];

        int tn = Mpad_[i] * Kp_[i];
        wtrans_kernel<<<dim3((tn + 255) / 256), dim3(256), 0, stream>>>(
            Wt, Abf[i], M, Mpad_[i], K2, C, Cp_[i], Kp_[i], C * K2);

        dim3 mgrid(N / BNT, Mpad_[i] / BMT);
        sconv_mfma_kernel<<<mgrid, dim3(256), 0, stream>>>(
            Abf[i], bias, c.s1, c.s2, c.C1, C, Cp_[i], H, W, c.up,
            K2, k, st, lWo, lHo, c.delta,
            c.Y, M, Kp_[i], N);

        bn_stats_part_kernel<<<dim3(M, SPLIT), dim3(256), 0, stream>>>(
            c.Y, part, M, HW, B);
        int total = B * M * HW;
        bn_apply_kernel<<<dim3(total / 256), dim3(256), 0, stream>>>(
            c.Y, part, gam, bet, M, HW, B, total);
    }
}